// Round 1
// baseline (267.139 us; speedup 1.0000x reference)
//
#include <hip/hip_runtime.h>
#include <hip/hip_bf16.h>

// Problem constants
#define B_    8
#define Qn    16
#define S_    4096
#define Hh    32
#define KVH_  8
#define D_    128
#define G_    4
#define ROWS  64          // G_*Qn rows of the score matrix per (b,kvh)
#define KT    128         // tokens per inner tile
#define THREADS 256

#define QS_STRIDE 132     // floats per q row in LDS (pad for bank spread)
#define PT_STRIDE 136     // shorts per P~ row in LDS

typedef unsigned int u32;
typedef unsigned short u16;

__device__ __forceinline__ float bfu_lo(u32 u){ union{u32 x; float f;} t; t.x = u << 16; return t.f; }
__device__ __forceinline__ float bfu_hi(u32 u){ union{u32 x; float f;} t; t.x = u & 0xffff0000u; return t.f; }
__device__ __forceinline__ u16 f2bf(float f){
  union{float f; u32 u;} t; t.f = f; u32 u = t.u;
  return (u16)((u + 0x7fffu + ((u >> 16) & 1u)) >> 16);   // RNE
}
__device__ __forceinline__ u16 quant1(float x, float inv){
  float nf = rintf(x * inv);                 // round-half-even, matches jnp.round
  nf = fminf(7.f, fmaxf(-8.f, nf));
  return f2bf(nf);                           // small ints exact in bf16
}
// swizzled index into a [KT][128] bf16 tile: 16B granules XORed by row>>3
__device__ __forceinline__ int swz(int row, int d){
  return row * D_ + ((((d >> 3) ^ ((row >> 3) & 7)) << 3) | (d & 7));
}

__global__ __launch_bounds__(THREADS, 1)
void attn_partial(const float* __restrict__ q, const float* __restrict__ k,
                  const float* __restrict__ v, float* __restrict__ part_o,
                  float* __restrict__ part_ml, int nchunk)
{
  __shared__ float qs[ROWS * QS_STRIDE];       // 33792 B
  __shared__ u16   kn[KT * D_];                // 32768 B (swizzled nibbles as bf16)
  __shared__ u16   vn[KT * D_];                // 32768 B (swizzled)
  __shared__ u16   pt[ROWS * PT_STRIDE];       // 17408 B (P * vscale, bf16)
  __shared__ float kscale[KT];
  __shared__ float vscale[KT];

  const int chunk = blockIdx.x;
  const int kvh   = blockIdx.y;
  const int b     = blockIdx.z;
  const int tid   = threadIdx.x;
  const int chunk_tokens = S_ / nchunk;
  const int nt    = chunk_tokens / KT;
  const int s_chunk = chunk * chunk_tokens;

  // ---- load q tile: 64 rows x 128, 4 threads per row ----
  {
    const int row = tid >> 2;                  // 0..63
    const int qd  = (tid & 3) * 32;
    const int g = row >> 4, qi = row & 15;
    const float* src = q + (((size_t)(b * Qn + qi) * Hh) + (kvh * G_ + g)) * (size_t)D_ + qd;
    float* dst = qs + row * QS_STRIDE + qd;
    #pragma unroll
    for (int m = 0; m < 8; ++m)
      *(float4*)(dst + m * 4) = *(const float4*)(src + m * 4);
  }

  const int ty = tid >> 4;                     // 0..15 -> rows r0..r0+3
  const int tx = tid & 15;                     // cols tx*8..tx*8+7 (tokens) / d-cols in PV
  const int r0 = ty * 4;
  const float RS = 0.08838834764831844f;       // 1/sqrt(128)

  float m_i[4], l_i[4], acc_o[4][8];
  #pragma unroll
  for (int i = 0; i < 4; ++i){
    m_i[i] = -1e30f; l_i[i] = 0.f;
    #pragma unroll
    for (int j = 0; j < 8; ++j) acc_o[i][j] = 0.f;
  }

  for (int t = 0; t < nt; ++t){
    const int s0 = s_chunk + t * KT;
    __syncthreads();                           // protect kn/vn/pt vs previous PV

    // ---- stage K & V tile: quantize to nibble (bf16), per-token scale ----
    #pragma unroll
    for (int pass = 0; pass < 2; ++pass){
      const int lt = pass * 64 + (tid >> 2);   // local token 0..127
      const int qd = (tid & 3) * 32;
      const size_t gbase = ((size_t)(b * S_ + s0 + lt) * KVH_ + kvh) * (size_t)D_ + qd;
      float4 kv4[8], vv4[8];
      float kam = 0.f, vam = 0.f;
      #pragma unroll
      for (int m = 0; m < 8; ++m){
        kv4[m] = *(const float4*)(k + gbase + m * 4);
        vv4[m] = *(const float4*)(v + gbase + m * 4);
        kam = fmaxf(kam, fmaxf(fmaxf(fabsf(kv4[m].x), fabsf(kv4[m].y)),
                               fmaxf(fabsf(kv4[m].z), fabsf(kv4[m].w))));
        vam = fmaxf(vam, fmaxf(fmaxf(fabsf(vv4[m].x), fabsf(vv4[m].y)),
                               fmaxf(fabsf(vv4[m].z), fabsf(vv4[m].w))));
      }
      kam = fmaxf(kam, __shfl_xor(kam, 1)); kam = fmaxf(kam, __shfl_xor(kam, 2));
      vam = fmaxf(vam, __shfl_xor(vam, 1)); vam = fmaxf(vam, __shfl_xor(vam, 2));
      const float ksc = fmaxf(kam * (1.f / 7.f), 1e-8f);
      const float vsc = fmaxf(vam * (1.f / 7.f), 1e-8f);
      if ((tid & 3) == 0){ kscale[lt] = ksc; vscale[lt] = vsc; }
      const float kinv = 1.f / ksc, vinv = 1.f / vsc;
      #pragma unroll
      for (int m = 0; m < 8; ++m){
        const int d = qd + m * 4;
        const int idx = swz(lt, d);
        ushort4 a = make_ushort4(quant1(kv4[m].x, kinv), quant1(kv4[m].y, kinv),
                                 quant1(kv4[m].z, kinv), quant1(kv4[m].w, kinv));
        ushort4 c = make_ushort4(quant1(vv4[m].x, vinv), quant1(vv4[m].y, vinv),
                                 quant1(vv4[m].z, vinv), quant1(vv4[m].w, vinv));
        *(ushort4*)&kn[idx] = a;
        *(ushort4*)&vn[idx] = c;
      }
    }
    __syncthreads();

    // ---- QK^T: 64 rows x 128 tokens, 4x8 per thread ----
    float accs[4][8];
    #pragma unroll
    for (int i = 0; i < 4; ++i)
      #pragma unroll
      for (int j = 0; j < 8; ++j) accs[i][j] = 0.f;

    #pragma unroll 4
    for (int kb = 0; kb < 16; ++kb){
      float4 qa[4], qb_[4];
      #pragma unroll
      for (int i = 0; i < 4; ++i){
        const float* qp = &qs[(r0 + i) * QS_STRIDE + kb * 8];
        qa[i]  = *(const float4*)qp;
        qb_[i] = *(const float4*)(qp + 4);
      }
      #pragma unroll
      for (int j = 0; j < 8; ++j){
        const int row = (tx << 3) + j;
        const uint4 kw = *(const uint4*)&kn[row * D_ + ((kb ^ (tx & 7)) << 3)];
        const float k0 = bfu_lo(kw.x), k1 = bfu_hi(kw.x), k2 = bfu_lo(kw.y), k3 = bfu_hi(kw.y);
        const float k4 = bfu_lo(kw.z), k5 = bfu_hi(kw.z), k6 = bfu_lo(kw.w), k7 = bfu_hi(kw.w);
        #pragma unroll
        for (int i = 0; i < 4; ++i){
          float s = accs[i][j];
          s = fmaf(qa[i].x,  k0, s); s = fmaf(qa[i].y,  k1, s);
          s = fmaf(qa[i].z,  k2, s); s = fmaf(qa[i].w,  k3, s);
          s = fmaf(qb_[i].x, k4, s); s = fmaf(qb_[i].y, k5, s);
          s = fmaf(qb_[i].z, k6, s); s = fmaf(qb_[i].w, k7, s);
          accs[i][j] = s;
        }
      }
    }

    // ---- online softmax (16-lane butterfly per row) + P~ write ----
    float sc8[8], vs8[8];
    #pragma unroll
    for (int j = 0; j < 8; ++j){ sc8[j] = kscale[(tx << 3) + j]; vs8[j] = vscale[(tx << 3) + j]; }
    #pragma unroll
    for (int i = 0; i < 4; ++i){
      const int qi = (r0 + i) & 15;
      const int slim = S_ - Qn + qi;           // valid s <= slim
      float sv[8]; float rowm = -1e30f;
      #pragma unroll
      for (int j = 0; j < 8; ++j){
        float x = accs[i][j] * sc8[j] * RS;
        if (s0 + (tx << 3) + j > slim) x = -1e30f;
        sv[j] = x; rowm = fmaxf(rowm, x);
      }
      rowm = fmaxf(rowm, __shfl_xor(rowm, 1));
      rowm = fmaxf(rowm, __shfl_xor(rowm, 2));
      rowm = fmaxf(rowm, __shfl_xor(rowm, 4));
      rowm = fmaxf(rowm, __shfl_xor(rowm, 8));
      const float mnew = fmaxf(m_i[i], rowm);
      const float fac = __expf(m_i[i] - mnew);
      float rsum = 0.f; u16 pw[8];
      #pragma unroll
      for (int j = 0; j < 8; ++j){
        const float p = __expf(sv[j] - mnew);
        rsum += p;
        pw[j] = f2bf(p * vs8[j]);              // fold vscale into P~
      }
      rsum += __shfl_xor(rsum, 1); rsum += __shfl_xor(rsum, 2);
      rsum += __shfl_xor(rsum, 4); rsum += __shfl_xor(rsum, 8);
      l_i[i] = l_i[i] * fac + rsum;
      m_i[i] = mnew;
      #pragma unroll
      for (int j = 0; j < 8; ++j) acc_o[i][j] *= fac;
      *(ushort4*)&pt[(r0 + i) * PT_STRIDE + (tx << 3)]     = make_ushort4(pw[0], pw[1], pw[2], pw[3]);
      *(ushort4*)&pt[(r0 + i) * PT_STRIDE + (tx << 3) + 4] = make_ushort4(pw[4], pw[5], pw[6], pw[7]);
    }
    __syncthreads();

    // ---- PV: acc_o[64][128] += P~ (64xKT) x nib_v (KTx128), 4x8 per thread ----
    const int d0 = tx << 3;
    #pragma unroll 4
    for (int cb = 0; cb < 16; ++cb){
      float pf[4][8];
      #pragma unroll
      for (int i = 0; i < 4; ++i){
        const uint4 pw_ = *(const uint4*)&pt[(r0 + i) * PT_STRIDE + (cb << 3)];
        pf[i][0] = bfu_lo(pw_.x); pf[i][1] = bfu_hi(pw_.x);
        pf[i][2] = bfu_lo(pw_.y); pf[i][3] = bfu_hi(pw_.y);
        pf[i][4] = bfu_lo(pw_.z); pf[i][5] = bfu_hi(pw_.z);
        pf[i][6] = bfu_lo(pw_.w); pf[i][7] = bfu_hi(pw_.w);
      }
      #pragma unroll
      for (int c = 0; c < 8; ++c){
        const int row = (cb << 3) + c;
        const uint4 vw = *(const uint4*)&vn[row * D_ + (((tx ^ ((row >> 3) & 7)) << 3))];
        const float v0 = bfu_lo(vw.x), v1 = bfu_hi(vw.x), v2 = bfu_lo(vw.y), v3 = bfu_hi(vw.y);
        const float v4 = bfu_lo(vw.z), v5 = bfu_hi(vw.z), v6 = bfu_lo(vw.w), v7 = bfu_hi(vw.w);
        #pragma unroll
        for (int i = 0; i < 4; ++i){
          const float p = pf[i][c];
          acc_o[i][0] = fmaf(p, v0, acc_o[i][0]); acc_o[i][1] = fmaf(p, v1, acc_o[i][1]);
          acc_o[i][2] = fmaf(p, v2, acc_o[i][2]); acc_o[i][3] = fmaf(p, v3, acc_o[i][3]);
          acc_o[i][4] = fmaf(p, v4, acc_o[i][4]); acc_o[i][5] = fmaf(p, v5, acc_o[i][5]);
          acc_o[i][6] = fmaf(p, v6, acc_o[i][6]); acc_o[i][7] = fmaf(p, v7, acc_o[i][7]);
        }
      }
    }
  }

  // ---- write partials (unnormalized O, m, l) ----
  {
    const size_t base = (((size_t)b * KVH_ + kvh) * (size_t)nchunk + chunk) * ROWS;
    #pragma unroll
    for (int i = 0; i < 4; ++i){
      float* dst = part_o + (base + r0 + i) * D_ + (tx << 3);
      *(float4*)dst       = make_float4(acc_o[i][0], acc_o[i][1], acc_o[i][2], acc_o[i][3]);
      *(float4*)(dst + 4) = make_float4(acc_o[i][4], acc_o[i][5], acc_o[i][6], acc_o[i][7]);
      if (tx == 0){
        part_ml[(base + r0 + i) * 2 + 0] = m_i[i];
        part_ml[(base + r0 + i) * 2 + 1] = l_i[i];
      }
    }
  }
}

__global__ void attn_reduce(const float* __restrict__ part_o, const float* __restrict__ part_ml,
                            float* __restrict__ out, int nchunk)
{
  const int row = blockIdx.x;   // 0..63
  const int kvh = blockIdx.y;
  const int b   = blockIdx.z;
  const int d   = threadIdx.x;  // 0..127
  const size_t base = ((size_t)b * KVH_ + kvh) * (size_t)nchunk;

  float M = -1e30f;
  for (int c = 0; c < nchunk; ++c)
    M = fmaxf(M, part_ml[((base + c) * ROWS + row) * 2 + 0]);
  float acc = 0.f, lt = 0.f;
  for (int c = 0; c < nchunk; ++c){
    const float m = part_ml[((base + c) * ROWS + row) * 2 + 0];
    const float l = part_ml[((base + c) * ROWS + row) * 2 + 1];
    const float w = __expf(m - M);
    lt += w * l;
    acc += w * part_o[((base + c) * ROWS + row) * D_ + d];
  }
  const int g = row >> 4, qi = row & 15;
  out[(((size_t)b * Qn + qi) * Hh + kvh * G_ + g) * (size_t)D_ + d] = acc / lt;
}

extern "C" void kernel_launch(void* const* d_in, const int* in_sizes, int n_in,
                              void* d_out, int out_size, void* d_ws, size_t ws_size,
                              hipStream_t stream)
{
  const float* q = (const float*)d_in[0];
  const float* k = (const float*)d_in[1];
  const float* v = (const float*)d_in[2];
  // d_in[3] = block_table: an injective permutation -> scatter/gather round-trip
  // is the identity; the ECC encode/decode round-trip (no injected errors) is
  // also the identity on the nibble. Neither needs to be materialized.
  float* out = (float*)d_out;

  int nchunk = 16;
  while (nchunk > 1 &&
         ((size_t)(524288 + 8192) * (size_t)nchunk * 4ull) > ws_size)
    nchunk >>= 1;

  float* part_o  = (float*)d_ws;
  float* part_ml = part_o + (size_t)524288 * (size_t)nchunk;

  attn_partial<<<dim3(nchunk, KVH_, B_), THREADS, 0, stream>>>(q, k, v, part_o, part_ml, nchunk);
  attn_reduce<<<dim3(ROWS, KVH_, B_), 128, 0, stream>>>(part_o, part_ml, out, nchunk);
}

// Round 2
// 112.054 us; speedup vs baseline: 2.3840x; 2.3840x over previous
//
#include <hip/hip_runtime.h>
#include <hip/hip_bf16.h>

// Problem constants
#define B_    8
#define Qn    16
#define S_    4096
#define Hh    32
#define KVH_  8
#define D_    128
#define G_    4
#define ROWS  64          // G_*Qn score rows per (b,kvh)
#define KT    64          // tokens per inner tile
#define THREADS 256

typedef unsigned int u32;
typedef unsigned short u16;
typedef __attribute__((ext_vector_type(8))) short short8;   // 8 bf16 (4 VGPRs)
typedef __attribute__((ext_vector_type(4))) float f32x4;    // MFMA C/D

__device__ __forceinline__ u16 f2bf(float f){
  union{float f; u32 u;} t; t.f = f; u32 u = t.u;
  return (u16)((u + 0x7fffu + ((u >> 16) & 1u)) >> 16);   // RNE
}
__device__ __forceinline__ float bf2f(u16 h){
  union{u32 x; float f;} t; t.x = ((u32)h) << 16; return t.f;
}
__device__ __forceinline__ u16 quant1(float x, float inv){
  float nf = rintf(x * inv);                 // matches jnp.round (RNE)
  nf = fminf(7.f, fmaxf(-8.f, nf));
  return f2bf(nf);                           // small ints exact in bf16
}

// attn_partial: grid (nchunk, KVH_, B_) x 256 threads.
// Wave w (=head-in-group g) owns score rows w*16..w*16+15.
// LDS tiles use 16B-granule XOR swizzle: granule ^= (row&7)  (G4).
__global__ __launch_bounds__(THREADS, 3)
void attn_partial(const float* __restrict__ q, const float* __restrict__ k,
                  const float* __restrict__ v, float* __restrict__ part_o,
                  float* __restrict__ part_ml, int nchunk)
{
  __shared__ u16 kn[KT * D_];     // [tok][d]   quantized K, swizzled   16 KB
  __shared__ u16 vt[D_ * KT];     // [d][tok]   quantized V^T, swizzled 16 KB
  __shared__ u16 pt[ROWS * KT];   // [qrow][tok] P~ = bf16(p*vscale)     8 KB
  __shared__ float kscale[KT];
  __shared__ float vscale[KT];

  const int chunk = blockIdx.x;
  const int kvh   = blockIdx.y;
  const int b     = blockIdx.z;
  const int tid   = threadIdx.x;
  const int lane  = tid & 63;
  const int w     = tid >> 6;                  // wave id == head group g
  const int l15   = lane & 15;
  const int l4    = lane >> 4;                 // 0..3
  const int chunk_tokens = S_ / nchunk;
  const int nt    = chunk_tokens / KT;
  const int s_chunk = chunk * chunk_tokens;
  const float RS = 0.08838834764831844f;       // 1/sqrt(128)

  // ---- Q fragments (hi/lo bf16 split) straight into registers ----
  // A-frag for 16x16x32: lane holds A[row=l15][k = kc*32 + l4*8 + i]
  short8 qhi[4], qlo[4];
  {
    const int h = kvh * G_ + w;
    const float* qp = q + (((size_t)(b * Qn + l15) * Hh) + h) * (size_t)D_ + (l4 * 8);
    #pragma unroll
    for (int kc = 0; kc < 4; ++kc){
      const float4 a = *(const float4*)(qp + kc * 32);
      const float4 c = *(const float4*)(qp + kc * 32 + 4);
      const float fv[8] = {a.x, a.y, a.z, a.w, c.x, c.y, c.z, c.w};
      #pragma unroll
      for (int i = 0; i < 8; ++i){
        const u16 hi = f2bf(fv[i]);
        qhi[kc][i] = (short)hi;
        qlo[kc][i] = (short)f2bf(fv[i] - bf2f(hi));
      }
    }
  }

  float m_i[4], l_i[4];
  f32x4 acc_o[8];                              // col d = df*16+l15, row = l4*4+reg
  #pragma unroll
  for (int r = 0; r < 4; ++r){ m_i[r] = -1e30f; l_i[r] = 0.f; }
  #pragma unroll
  for (int df = 0; df < 8; ++df) acc_o[df] = (f32x4)0.f;

  for (int t = 0; t < nt; ++t){
    const int s0 = s_chunk + t * KT;
    __syncthreads();                           // prev PV done reading vt/pt

    // ---- stage K tile: quantize to signed nibble value in bf16 ----
    {
      const int lt = tid >> 2;                 // token 0..63
      const int qd = (tid & 3) * 32;
      const size_t gb = ((size_t)(b * S_ + s0 + lt) * KVH_ + kvh) * (size_t)D_ + qd;
      float4 r[8]; float am = 0.f;
      #pragma unroll
      for (int m = 0; m < 8; ++m){
        r[m] = *(const float4*)(k + gb + m * 4);
        am = fmaxf(am, fmaxf(fmaxf(fabsf(r[m].x), fabsf(r[m].y)),
                             fmaxf(fabsf(r[m].z), fabsf(r[m].w))));
      }
      am = fmaxf(am, __shfl_xor(am, 1));
      am = fmaxf(am, __shfl_xor(am, 2));
      const float sc = fmaxf(am * (1.f / 7.f), 1e-8f);
      if ((tid & 3) == 0) kscale[lt] = sc;
      const float inv = 1.f / sc;
      #pragma unroll
      for (int m = 0; m < 8; ++m){
        const int d = qd + m * 4;
        const int idx = lt * D_ + ((((d >> 3) ^ (lt & 7)) << 3) | (d & 7));
        *(ushort4*)&kn[idx] = make_ushort4(quant1(r[m].x, inv), quant1(r[m].y, inv),
                                           quant1(r[m].z, inv), quant1(r[m].w, inv));
      }
    }
    // ---- stage V tile transposed: vt[d][tok] ----
    {
      const int lt = tid >> 2;
      const int qd = (tid & 3) * 32;
      const size_t gb = ((size_t)(b * S_ + s0 + lt) * KVH_ + kvh) * (size_t)D_ + qd;
      float4 r[8]; float am = 0.f;
      #pragma unroll
      for (int m = 0; m < 8; ++m){
        r[m] = *(const float4*)(v + gb + m * 4);
        am = fmaxf(am, fmaxf(fmaxf(fabsf(r[m].x), fabsf(r[m].y)),
                             fmaxf(fabsf(r[m].z), fabsf(r[m].w))));
      }
      am = fmaxf(am, __shfl_xor(am, 1));
      am = fmaxf(am, __shfl_xor(am, 2));
      const float sc = fmaxf(am * (1.f / 7.f), 1e-8f);
      if ((tid & 3) == 0) vscale[lt] = sc;
      const float inv = 1.f / sc;
      #pragma unroll
      for (int m = 0; m < 8; ++m){
        const int d0 = qd + m * 4;
        const u16 n0 = quant1(r[m].x, inv), n1 = quant1(r[m].y, inv);
        const u16 n2 = quant1(r[m].z, inv), n3 = quant1(r[m].w, inv);
        vt[(d0 + 0) * KT + ((((lt >> 3) ^ ((d0 + 0) & 7)) << 3) | (lt & 7))] = n0;
        vt[(d0 + 1) * KT + ((((lt >> 3) ^ ((d0 + 1) & 7)) << 3) | (lt & 7))] = n1;
        vt[(d0 + 2) * KT + ((((lt >> 3) ^ ((d0 + 2) & 7)) << 3) | (lt & 7))] = n2;
        vt[(d0 + 3) * KT + ((((lt >> 3) ^ ((d0 + 3) & 7)) << 3) | (lt & 7))] = n3;
      }
    }
    __syncthreads();

    // ---- QK^T via MFMA: wave computes 16 rows x 64 tokens ----
    f32x4 st[4];
    #pragma unroll
    for (int cf = 0; cf < 4; ++cf) st[cf] = (f32x4)0.f;
    #pragma unroll
    for (int kc = 0; kc < 4; ++kc){
      #pragma unroll
      for (int cf = 0; cf < 4; ++cf){
        const int tok = cf * 16 + l15;
        const int gr  = kc * 4 + l4;           // d-granule 0..15
        const short8 kf = *(const short8*)&kn[tok * D_ + ((gr ^ (tok & 7)) << 3)];
        st[cf] = __builtin_amdgcn_mfma_f32_16x16x32_bf16(qhi[kc], kf, st[cf], 0, 0, 0);
        st[cf] = __builtin_amdgcn_mfma_f32_16x16x32_bf16(qlo[kc], kf, st[cf], 0, 0, 0);
      }
    }

    // ---- online softmax (rows = l4*4+reg, tokens over cf x l15) ----
    float sc8[4], vs8[4];
    #pragma unroll
    for (int cf = 0; cf < 4; ++cf){
      sc8[cf] = kscale[cf * 16 + l15] * RS;
      vs8[cf] = vscale[cf * 16 + l15];
    }
    f32x4 facv;
    #pragma unroll
    for (int r = 0; r < 4; ++r){
      const int qi   = (l4 << 2) + r;          // 0..15 == query index
      const int slim = S_ - Qn + qi;
      float xr[4]; float rm = -1e30f;
      #pragma unroll
      for (int cf = 0; cf < 4; ++cf){
        float x = st[cf][r] * sc8[cf];
        if (s0 + cf * 16 + l15 > slim) x = -1e30f;
        xr[cf] = x; rm = fmaxf(rm, x);
      }
      rm = fmaxf(rm, __shfl_xor(rm, 1));
      rm = fmaxf(rm, __shfl_xor(rm, 2));
      rm = fmaxf(rm, __shfl_xor(rm, 4));
      rm = fmaxf(rm, __shfl_xor(rm, 8));
      const float mn  = fmaxf(m_i[r], rm);
      const float fac = __expf(m_i[r] - mn);
      float rs = 0.f; u16 pw[4];
      #pragma unroll
      for (int cf = 0; cf < 4; ++cf){
        const float p = __expf(xr[cf] - mn);
        rs += p;
        pw[cf] = f2bf(p * vs8[cf]);            // fold vscale into P~
      }
      rs += __shfl_xor(rs, 1); rs += __shfl_xor(rs, 2);
      rs += __shfl_xor(rs, 4); rs += __shfl_xor(rs, 8);
      l_i[r] = l_i[r] * fac + rs;
      m_i[r] = mn;
      facv[r] = fac;
      const int qrow = (w << 4) + qi;
      #pragma unroll
      for (int cf = 0; cf < 4; ++cf){
        const int tok = cf * 16 + l15;
        pt[qrow * KT + ((((tok >> 3) ^ (qrow & 7)) << 3) | (tok & 7))] = pw[cf];
      }
    }
    #pragma unroll
    for (int df = 0; df < 8; ++df) acc_o[df] *= facv;
    __syncthreads();                           // pt/vt ready for PV

    // ---- PV via MFMA: A = P~ (16 rows x 32 tok), B = V (tok x 16 d) ----
    #pragma unroll
    for (int tc = 0; tc < 2; ++tc){
      const int qrow = (w << 4) + l15;
      const int gr   = tc * 4 + l4;            // token granule 0..7
      const short8 pf = *(const short8*)&pt[qrow * KT + ((gr ^ (qrow & 7)) << 3)];
      #pragma unroll
      for (int df = 0; df < 8; ++df){
        const int d = df * 16 + l15;
        const short8 vf = *(const short8*)&vt[d * KT + ((gr ^ (d & 7)) << 3)];
        acc_o[df] = __builtin_amdgcn_mfma_f32_16x16x32_bf16(pf, vf, acc_o[df], 0, 0, 0);
      }
    }
  }

  // ---- write partials (unnormalized O, m, l) ----
  {
    const size_t base = (((size_t)b * KVH_ + kvh) * (size_t)nchunk + chunk) * ROWS;
    #pragma unroll
    for (int r = 0; r < 4; ++r){
      const int qrow = (w << 4) + (l4 << 2) + r;
      #pragma unroll
      for (int df = 0; df < 8; ++df)
        part_o[(base + qrow) * D_ + df * 16 + l15] = acc_o[df][r];
      if (l15 == 0){
        part_ml[(base + qrow) * 2 + 0] = m_i[r];
        part_ml[(base + qrow) * 2 + 1] = l_i[r];
      }
    }
  }
}

__global__ void attn_reduce(const float* __restrict__ part_o, const float* __restrict__ part_ml,
                            float* __restrict__ out, int nchunk)
{
  const int row = blockIdx.x;   // 0..63  (= g*16 + qi)
  const int kvh = blockIdx.y;
  const int b   = blockIdx.z;
  const int d   = threadIdx.x;  // 0..127
  const size_t base = ((size_t)b * KVH_ + kvh) * (size_t)nchunk;

  float M = -1e30f;
  for (int c = 0; c < nchunk; ++c)
    M = fmaxf(M, part_ml[((base + c) * ROWS + row) * 2 + 0]);
  float acc = 0.f, lt = 0.f;
  for (int c = 0; c < nchunk; ++c){
    const float m = part_ml[((base + c) * ROWS + row) * 2 + 0];
    const float l = part_ml[((base + c) * ROWS + row) * 2 + 1];
    const float w = __expf(m - M);
    lt += w * l;
    acc += w * part_o[((base + c) * ROWS + row) * D_ + d];
  }
  const int g = row >> 4, qi = row & 15;
  out[(((size_t)b * Qn + qi) * Hh + kvh * G_ + g) * (size_t)D_ + d] = acc / lt;
}

extern "C" void kernel_launch(void* const* d_in, const int* in_sizes, int n_in,
                              void* d_out, int out_size, void* d_ws, size_t ws_size,
                              hipStream_t stream)
{
  const float* q = (const float*)d_in[0];
  const float* k = (const float*)d_in[1];
  const float* v = (const float*)d_in[2];
  // d_in[3] = block_table: identity permutation round-trip; ECC encode/decode
  // with no injected errors is the identity on the nibble -> fake-quant only.
  float* out = (float*)d_out;

  int nchunk = 16;
  while (nchunk > 1 &&
         ((size_t)(524288 + 8192) * (size_t)nchunk * 4ull) > ws_size)
    nchunk >>= 1;

  float* part_o  = (float*)d_ws;
  float* part_ml = part_o + (size_t)524288 * (size_t)nchunk;

  attn_partial<<<dim3(nchunk, KVH_, B_), THREADS, 0, stream>>>(q, k, v, part_o, part_ml, nchunk);
  attn_reduce<<<dim3(ROWS, KVH_, B_), 128, 0, stream>>>(part_o, part_ml, out, nchunk);
}